// Round 10
// baseline (2214.037 us; speedup 1.0000x reference)
//
#include <hip/hip_runtime.h>
#include <hip/hip_bf16.h>

#define NND 100000
#define NED 3200000
#define F 256
#define NCLS 64
#define NC 100               // coarse dst bins of 1000 nodes (build)
#define MAXPER 36000         // slack per bin (mean 32000, sigma ~178)
#define EBLK 4096            // edges per pass-A block
#define NSB 7                // src blocks of 16384 nodes (sb = src >> 14)
#define HOPBLK 250

typedef _Float16 f16x8 __attribute__((ext_vector_type(8)));
typedef _Float16 f16x4 __attribute__((ext_vector_type(4)));
typedef _Float16 f16x2 __attribute__((ext_vector_type(2)));
typedef float f32x4 __attribute__((ext_vector_type(4)));

// ---------------- init per-bin global cursors ----------------
__global__ void k_init(int* __restrict__ gcur) {
    int b = threadIdx.x;
    if (b < NC) gcur[b] = b * MAXPER;
}

// ---------------- pass A: block-aggregated coarse binning, coalesced flush ----------------
__global__ __launch_bounds__(256) void k_passA(const int* __restrict__ src, const int* __restrict__ dst,
                                               int* __restrict__ gcur, int2* __restrict__ binned) {
    __shared__ int hist[NC], scn[NC], cur[NC], gbase[NC];
    __shared__ int2 stage[EBLK];
    __shared__ unsigned char bkt[EBLK];
    int base = blockIdx.x * EBLK;
    int n = NED - base; if (n > EBLK) n = EBLK;
    int t = threadIdx.x;
    if (t < NC) hist[t] = 0;
    __syncthreads();
    for (int i = t; i < n; i += 256) atomicAdd(&hist[dst[base + i] / 1000], 1);
    __syncthreads();
    if (t == 0) {
        int run = 0;
        for (int b = 0; b < NC; b++) { scn[b] = run; cur[b] = run; run += hist[b]; }
    }
    __syncthreads();
    if (t < NC) gbase[t] = atomicAdd(&gcur[t], hist[t]);
    __syncthreads();
    for (int i = t; i < n; i += 256) {
        int s = src[base + i], d = dst[base + i];
        int b = d / 1000;
        int r = atomicAdd(&cur[b], 1);
        stage[r] = make_int2(s, d);
        bkt[r] = (unsigned char)b;
    }
    __syncthreads();
    for (int i = t; i < n; i += 256) {
        int b = bkt[i];
        binned[gbase[b] + (i - scn[b])] = stage[i];
    }
}

// ---------------- pass B: per-bin (wave, srcblk, localnode) bucketing + norm ----------------
// bin = 1000 dst nodes = 40 waves x 25. key = lw*175 + sb*25 + ln  (7000 keys)
__global__ __launch_bounds__(1024) void k_passB(const int2* __restrict__ binned, const int* __restrict__ gcur,
                                                float* __restrict__ norm, int* __restrict__ col2,
                                                int* __restrict__ ebs, int* __restrict__ ebc) {
    __shared__ int h[7000], cur[7000], psum[1024];
    int b = blockIdx.x;
    int t = threadIdx.x;
    int n = gcur[b] - b * MAXPER;
    const int2* eb = binned + (size_t)b * MAXPER;
    for (int k = t; k < 7000; k += 1024) h[k] = 0;
    __syncthreads();
    for (int i = t; i < n; i += 1024) {
        int2 e = eb[i];
        int dl = e.y - b * 1000;          // 0..999
        int lw = dl / 25, ln = dl - lw * 25;
        int sb = e.x >> 14;
        atomicAdd(&h[lw * 175 + sb * 25 + ln], 1);
    }
    __syncthreads();
    // per-node degree -> norm (before h is overwritten)
    if (t < 1000) {
        int lw = t / 25, ln = t - lw * 25;
        int d = 0;
#pragma unroll
        for (int sb = 0; sb < NSB; sb++) d += h[lw * 175 + sb * 25 + ln];
        float df = (float)d;
        norm[b * 1000 + t] = rsqrtf(df < 1.0f ? 1.0f : df);
    }
    __syncthreads();
    // exclusive scan of h[7000]: threads 0..999 own keys [7t, 7t+7)  (FIX: guard t<1000)
    int c[7] = {0, 0, 0, 0, 0, 0, 0};
    int s = 0;
    if (t < 1000) {
#pragma unroll
        for (int k = 0; k < 7; k++) { c[k] = h[t * 7 + k]; s += c[k]; }
    }
    psum[t] = s;
    __syncthreads();
    for (int off = 1; off < 1024; off <<= 1) {
        int v = (t >= off) ? psum[t - off] : 0;
        __syncthreads();
        psum[t] += v;
        __syncthreads();
    }
    if (t < 1000) {
        int run = psum[t] - s;
#pragma unroll
        for (int k = 0; k < 7; k++) { h[t * 7 + k] = run; cur[t * 7 + k] = run; run += c[k]; }
    }
    __syncthreads();
    // bucket starts/counts: 40 waves x 7 sb = 280 buckets
    if (t < 280) {
        int lw = t / 7, sb = t - lw * 7;
        int k0 = lw * 175 + sb * 25;
        int st = h[k0];
        int en = (k0 + 25 < 7000) ? h[k0 + 25] : n;
        ebs[(40 * b + lw) * NSB + sb] = b * MAXPER + st;
        ebc[(40 * b + lw) * NSB + sb] = en - st;
    }
    __syncthreads();
    // rank-scatter edge words (src<<5 | ln)
    for (int i = t; i < n; i += 1024) {
        int2 e = eb[i];
        int dl = e.y - b * 1000;
        int lw = dl / 25, ln = dl - lw * 25;
        int sb = e.x >> 14;
        int r = atomicAdd(&cur[lw * 175 + sb * 25 + ln], 1);
        col2[b * MAXPER + r] = (e.x << 5) | ln;
    }
}

// ---------------- LayerNorm (one wave per node) -> pre-scaled fp16 (norm * LN) ----------------
__global__ __launch_bounds__(256) void k_ln(const float* __restrict__ x, const float* __restrict__ gamma,
                                            const float* __restrict__ beta, const float* __restrict__ norm,
                                            _Float16* __restrict__ y) {
    int node = blockIdx.x * 4 + (threadIdx.x >> 6);
    int lane = threadIdx.x & 63;
    if (node >= NND) return;
    float4 v = ((const float4*)x)[node * 64 + lane];
    float s = v.x + v.y + v.z + v.w;
    float s2 = v.x * v.x + v.y * v.y + v.z * v.z + v.w * v.w;
    for (int m = 1; m < 64; m <<= 1) {
        s += __shfl_xor(s, m, 64);
        s2 += __shfl_xor(s2, m, 64);
    }
    float mu = s * (1.0f / 256.0f);
    float var = s2 * (1.0f / 256.0f) - mu * mu;
    float rs = rsqrtf(var + 1e-5f);
    float w = norm[node];
    float4 g = ((const float4*)gamma)[lane];
    float4 b = ((const float4*)beta)[lane];
    f16x4 o;
    o[0] = (_Float16)(w * ((v.x - mu) * rs * g.x + b.x));
    o[1] = (_Float16)(w * ((v.y - mu) * rs * g.y + b.y));
    o[2] = (_Float16)(w * ((v.z - mu) * rs * g.z + b.z));
    o[3] = (_Float16)(w * ((v.w - mu) * rs * g.w + b.w));
    *(f16x4*)(y + (size_t)node * F + lane * 4) = o;
}

// ---------------- aligned src-sweep hop, one feature half per launch ----------------
// 250 blocks x 1024 thr, 1 block/CU (102KB LDS). Block owns 400 dst nodes; wave owns 25.
// Soft global barrier between src-phases (locality only; timeout-safe).
template <int LAST>
__global__ __launch_bounds__(1024) void k_hop2(const _Float16* __restrict__ x, _Float16* __restrict__ y,
                                               const int* __restrict__ ebs, const int* __restrict__ ebc,
                                               const int* __restrict__ col2, const float* __restrict__ norm,
                                               int P, int* __restrict__ bar) {
    __shared__ _Float16 accu[400 * 128];   // 102,400 B
    int t = threadIdx.x;
    int wave = t >> 6, lane = t & 63;
    int gw = blockIdx.x * 16 + wave;
    for (int i = t; i < 25600; i += 1024) ((int*)accu)[i] = 0;
    __syncthreads();
    const _Float16* xb = x + P * 128;
    for (int sb = 0; sb < NSB; sb++) {
        int e0 = ebs[gw * NSB + sb];
        int e1 = e0 + ebc[gw * NSB + sb];
        for (int base = e0; base < e1; base += 64) {
            int m = e1 - base; if (m > 64) m = 64;
            int cv = col2[base + (lane < m ? lane : m - 1)];
            for (int j = 0; j < m; j++) {
                int wrd = __shfl(cv, j, 64);
                int ln = wrd & 31;
                int srcn = wrd >> 5;
                f16x2 v = *(const f16x2*)(xb + (size_t)srcn * F + lane * 2);
                f16x2* p = (f16x2*)&accu[((wave * 25 + ln) << 7) + lane * 2];
                *p = *p + v;
            }
        }
        if (sb < NSB - 1) {
            __syncthreads();
            if (t == 0) {
                __hip_atomic_fetch_add(bar, 1, __ATOMIC_RELAXED, __HIP_MEMORY_SCOPE_AGENT);
                int target = HOPBLK * (sb + 1);
                int it = 0;
                while (__hip_atomic_load(bar, __ATOMIC_RELAXED, __HIP_MEMORY_SCOPE_AGENT) < target
                       && ++it < 4096)
                    __builtin_amdgcn_s_sleep(4);
            }
            __syncthreads();
        }
    }
    __syncthreads();
    // write out: 400 nodes x 64 f16x2 slots
    for (int i = t; i < 400 * 64; i += 1024) {
        int nl = i >> 6, lp = i & 63;
        int node = blockIdx.x * 400 + nl;
        float wd = norm[node];
        float sc = LAST ? wd : wd * wd;
        f16x2 a = *(f16x2*)&accu[(nl << 7) + lp * 2];
        f16x2 o;
        o[0] = (_Float16)((float)a[0] * sc);
        o[1] = (_Float16)((float)a[1] * sc);
        *(f16x2*)(y + (size_t)node * F + P * 128 + lp * 2) = o;
    }
}

// ---------------- fp32 -> fp16 cast of both weight matrices ----------------
__global__ __launch_bounds__(256) void k_castW(const float4* __restrict__ Wc, const float4* __restrict__ Wf,
                                               f16x4* __restrict__ WcO, f16x4* __restrict__ WfO) {
    int i = blockIdx.x * 256 + threadIdx.x;
    if (i < F * F / 4) {
        float4 v = Wc[i];
        f16x4 o;
        o[0] = (_Float16)v.x; o[1] = (_Float16)v.y; o[2] = (_Float16)v.z; o[3] = (_Float16)v.w;
        WcO[i] = o;
    } else {
        int j = i - F * F / 4;
        if (j < NCLS * F / 4) {
            float4 v = Wf[j];
            f16x4 o;
            o[0] = (_Float16)v.x; o[1] = (_Float16)v.y; o[2] = (_Float16)v.z; o[3] = (_Float16)v.w;
            WfO[j] = o;
        }
    }
}

// ---------------- fused GEMM: relu(h3 @ Wc^T + bc) @ Wf^T + bf ----------------
__global__ __launch_bounds__(256) void k_gemm(const _Float16* __restrict__ A,
                                              const _Float16* __restrict__ Wc, const float* __restrict__ bc,
                                              const _Float16* __restrict__ Wf, const float* __restrict__ bf,
                                              float* __restrict__ out) {
    __shared__ _Float16 mid[16][264];
    int wave = threadIdx.x >> 6, lane = threadIdx.x & 63;
    int l15 = lane & 15, lhi = lane >> 4;
    int row0 = blockIdx.x * 16;
    const _Float16* arow = A + (size_t)(row0 + l15) * F + lhi * 8;
    int ncol0 = wave * 64;
    f32x4 acc[4];
    for (int t = 0; t < 4; t++) acc[t] = (f32x4){0.f, 0.f, 0.f, 0.f};
#pragma unroll
    for (int kt = 0; kt < 8; kt++) {
        f16x8 a = *(const f16x8*)(arow + kt * 32);
#pragma unroll
        for (int t = 0; t < 4; t++) {
            int n = ncol0 + t * 16 + l15;
            f16x8 b = *(const f16x8*)(Wc + (size_t)n * F + lhi * 8 + kt * 32);
            acc[t] = __builtin_amdgcn_mfma_f32_16x16x32_f16(a, b, acc[t], 0, 0, 0);
        }
    }
#pragma unroll
    for (int t = 0; t < 4; t++) {
        int colb = ncol0 + t * 16 + l15;
        float bv = bc[colb];
#pragma unroll
        for (int r = 0; r < 4; r++) {
            float v = acc[t][r] + bv;
            mid[lhi * 4 + r][colb] = (_Float16)(v > 0.f ? v : 0.f);
        }
    }
    __syncthreads();
    f32x4 acc2 = (f32x4){0.f, 0.f, 0.f, 0.f};
    int colb = wave * 16 + l15;
    const _Float16* brow = Wf + (size_t)colb * F + lhi * 8;
#pragma unroll
    for (int kt = 0; kt < 8; kt++) {
        f16x8 a = *(const f16x8*)&mid[l15][lhi * 8 + kt * 32];
        f16x8 b = *(const f16x8*)(brow + kt * 32);
        acc2 = __builtin_amdgcn_mfma_f32_16x16x32_f16(a, b, acc2, 0, 0, 0);
    }
    float bv = bf[colb];
#pragma unroll
    for (int r = 0; r < 4; r++) {
        int row = row0 + lhi * 4 + r;
        out[(size_t)row * NCLS + colb] = acc2[r] + bv;
    }
}

extern "C" void kernel_launch(void* const* d_in, const int* in_sizes, int n_in,
                              void* d_out, int out_size, void* d_ws, size_t ws_size,
                              hipStream_t stream) {
    const float* features = (const float*)d_in[0];
    const int* edge_src = (const int*)d_in[1];
    const int* edge_dst = (const int*)d_in[2];
    const float* ln_gamma = (const float*)d_in[3];
    const float* ln_beta = (const float*)d_in[4];
    const float* W_conv = (const float*)d_in[5];
    const float* b_conv = (const float*)d_in[6];
    const float* W_fc = (const float*)d_in[7];
    const float* b_fc = (const float*)d_in[8];
    float* out = (float*)d_out;

    char* w = (char*)d_ws;
    const size_t HB2 = (size_t)NND * F * 2;            // 51,200,000 (fp16 h)
    _Float16* hA = (_Float16*)(w + 0);
    int2* binned = (int2*)(w + 0);                     // 28.8 MB, aliases hA (dead before k_ln)
    _Float16* hB = (_Float16*)(w + HB2);
    int* col2 = (int*)(w + 102400000);                 // 14.4 MB
    float* norm = (float*)(w + 117000000);             // 400 KB
    int* ebs = (int*)(w + 117400000);                  // 112 KB
    int* ebc = (int*)(w + 117520000);                  // 112 KB
    int* gcur = (int*)(w + 117640000);                 // 400 B
    int* bar = (int*)(w + 117642048);                  // 6 counters
    _Float16* Wc16 = (_Float16*)(w + 117643072);
    _Float16* Wf16 = (_Float16*)(w + 117774144);

    k_init<<<1, 128, 0, stream>>>(gcur);
    k_passA<<<(NED + EBLK - 1) / EBLK, 256, 0, stream>>>(edge_src, edge_dst, gcur, binned);
    k_passB<<<NC, 1024, 0, stream>>>(binned, gcur, norm, col2, ebs, ebc);

    k_ln<<<NND / 4, 256, 0, stream>>>(features, ln_gamma, ln_beta, norm, hA);

    hipMemsetAsync(bar, 0, 64, stream);
    k_hop2<0><<<HOPBLK, 1024, 0, stream>>>(hA, hB, ebs, ebc, col2, norm, 0, bar + 0);
    k_hop2<0><<<HOPBLK, 1024, 0, stream>>>(hA, hB, ebs, ebc, col2, norm, 1, bar + 1);
    k_hop2<0><<<HOPBLK, 1024, 0, stream>>>(hB, hA, ebs, ebc, col2, norm, 0, bar + 2);
    k_hop2<0><<<HOPBLK, 1024, 0, stream>>>(hB, hA, ebs, ebc, col2, norm, 1, bar + 3);
    k_hop2<1><<<HOPBLK, 1024, 0, stream>>>(hA, hB, ebs, ebc, col2, norm, 0, bar + 4);
    k_hop2<1><<<HOPBLK, 1024, 0, stream>>>(hA, hB, ebs, ebc, col2, norm, 1, bar + 5);

    k_castW<<<(F * F / 4 + NCLS * F / 4 + 255) / 256, 256, 0, stream>>>(
        (const float4*)W_conv, (const float4*)W_fc, (f16x4*)Wc16, (f16x4*)Wf16);

    k_gemm<<<NND / 16, 256, 0, stream>>>(hB, Wc16, b_conv, Wf16, b_fc, out);
}

// Round 11
// 1865.628 us; speedup vs baseline: 1.1868x; 1.1868x over previous
//
#include <hip/hip_runtime.h>
#include <hip/hip_bf16.h>

#define NND 100000
#define NED 3200000
#define F 256
#define NCLS 64
#define NC 100               // coarse dst bins of 1000 nodes (build)
#define MAXPER 36000         // slack per bin (mean 32000, sigma ~178)
#define EBLK 4096            // edges per pass-A block
#define NSB 7                // src blocks of 16384 nodes (sb = src >> 14)
#define HOPBLK 250

typedef _Float16 f16x8 __attribute__((ext_vector_type(8)));
typedef _Float16 f16x4 __attribute__((ext_vector_type(4)));
typedef _Float16 f16x2 __attribute__((ext_vector_type(2)));
typedef float f32x4 __attribute__((ext_vector_type(4)));

// ---------------- init per-bin global cursors ----------------
__global__ void k_init(int* __restrict__ gcur) {
    int b = threadIdx.x;
    if (b < NC) gcur[b] = b * MAXPER;
}

// ---------------- pass A: block-aggregated coarse binning, coalesced flush ----------------
__global__ __launch_bounds__(256) void k_passA(const int* __restrict__ src, const int* __restrict__ dst,
                                               int* __restrict__ gcur, int2* __restrict__ binned) {
    __shared__ int hist[NC], scn[NC], cur[NC], gbase[NC];
    __shared__ int2 stage[EBLK];
    __shared__ unsigned char bkt[EBLK];
    int base = blockIdx.x * EBLK;
    int n = NED - base; if (n > EBLK) n = EBLK;
    int t = threadIdx.x;
    if (t < NC) hist[t] = 0;
    __syncthreads();
    for (int i = t; i < n; i += 256) atomicAdd(&hist[dst[base + i] / 1000], 1);
    __syncthreads();
    if (t == 0) {
        int run = 0;
        for (int b = 0; b < NC; b++) { scn[b] = run; cur[b] = run; run += hist[b]; }
    }
    __syncthreads();
    if (t < NC) gbase[t] = atomicAdd(&gcur[t], hist[t]);
    __syncthreads();
    for (int i = t; i < n; i += 256) {
        int s = src[base + i], d = dst[base + i];
        int b = d / 1000;
        int r = atomicAdd(&cur[b], 1);
        stage[r] = make_int2(s, d);
        bkt[r] = (unsigned char)b;
    }
    __syncthreads();
    for (int i = t; i < n; i += 256) {
        int b = bkt[i];
        binned[gbase[b] + (i - scn[b])] = stage[i];
    }
}

// ---------------- pass B: per-bin (wave, srcblk, localnode) bucketing + norm + run counts ----------------
// bin = 1000 dst nodes = 40 waves x 25. key = lw*175 + sb*25 + ln  (7000 keys)
__global__ __launch_bounds__(1024) void k_passB(const int2* __restrict__ binned, const int* __restrict__ gcur,
                                                float* __restrict__ norm, int* __restrict__ col2,
                                                int* __restrict__ ebs, unsigned char* __restrict__ cnts) {
    __shared__ int h[7000], cur[7000], psum[1024];
    int b = blockIdx.x;
    int t = threadIdx.x;
    int n = gcur[b] - b * MAXPER;
    const int2* eb = binned + (size_t)b * MAXPER;
    for (int k = t; k < 7000; k += 1024) h[k] = 0;
    __syncthreads();
    for (int i = t; i < n; i += 1024) {
        int2 e = eb[i];
        int dl = e.y - b * 1000;          // 0..999
        int lw = dl / 25, ln = dl - lw * 25;
        int sb = e.x >> 14;
        atomicAdd(&h[lw * 175 + sb * 25 + ln], 1);
    }
    __syncthreads();
    // per-node degree -> norm (before h is overwritten)
    if (t < 1000) {
        int lw = t / 25, ln = t - lw * 25;
        int d = 0;
#pragma unroll
        for (int sb = 0; sb < NSB; sb++) d += h[lw * 175 + sb * 25 + ln];
        float df = (float)d;
        norm[b * 1000 + t] = rsqrtf(df < 1.0f ? 1.0f : df);
    }
    __syncthreads();
    // exclusive scan of h[7000]: threads 0..999 own keys [7t, 7t+7)
    int c[7] = {0, 0, 0, 0, 0, 0, 0};
    int s = 0;
    if (t < 1000) {
#pragma unroll
        for (int k = 0; k < 7; k++) { c[k] = h[t * 7 + k]; s += c[k]; }
    }
    psum[t] = s;
    __syncthreads();
    for (int off = 1; off < 1024; off <<= 1) {
        int v = (t >= off) ? psum[t - off] : 0;
        __syncthreads();
        psum[t] += v;
        __syncthreads();
    }
    if (t < 1000) {
        int run = psum[t] - s;
#pragma unroll
        for (int k = 0; k < 7; k++) {
            h[t * 7 + k] = run; cur[t * 7 + k] = run; run += c[k];
            cnts[(size_t)b * 7000 + t * 7 + k] = (unsigned char)c[k];   // run lengths
        }
    }
    __syncthreads();
    // bucket starts: 40 waves x 7 sb = 280 buckets
    if (t < 280) {
        int lw = t / 7, sb = t - lw * 7;
        int k0 = lw * 175 + sb * 25;
        ebs[(40 * b + lw) * NSB + sb] = b * MAXPER + h[k0];
    }
    __syncthreads();
    // rank-scatter plain src ids (runs contiguous per key, key-ordered)
    for (int i = t; i < n; i += 1024) {
        int2 e = eb[i];
        int dl = e.y - b * 1000;
        int lw = dl / 25, ln = dl - lw * 25;
        int sb = e.x >> 14;
        int r = atomicAdd(&cur[lw * 175 + sb * 25 + ln], 1);
        col2[b * MAXPER + r] = e.x;
    }
}

// ---------------- LayerNorm (one wave per node) -> pre-scaled fp16 (norm * LN) ----------------
__global__ __launch_bounds__(256) void k_ln(const float* __restrict__ x, const float* __restrict__ gamma,
                                            const float* __restrict__ beta, const float* __restrict__ norm,
                                            _Float16* __restrict__ y) {
    int node = blockIdx.x * 4 + (threadIdx.x >> 6);
    int lane = threadIdx.x & 63;
    if (node >= NND) return;
    float4 v = ((const float4*)x)[node * 64 + lane];
    float s = v.x + v.y + v.z + v.w;
    float s2 = v.x * v.x + v.y * v.y + v.z * v.z + v.w * v.w;
    for (int m = 1; m < 64; m <<= 1) {
        s += __shfl_xor(s, m, 64);
        s2 += __shfl_xor(s2, m, 64);
    }
    float mu = s * (1.0f / 256.0f);
    float var = s2 * (1.0f / 256.0f) - mu * mu;
    float rs = rsqrtf(var + 1e-5f);
    float w = norm[node];
    float4 g = ((const float4*)gamma)[lane];
    float4 b = ((const float4*)beta)[lane];
    f16x4 o;
    o[0] = (_Float16)(w * ((v.x - mu) * rs * g.x + b.x));
    o[1] = (_Float16)(w * ((v.y - mu) * rs * g.y + b.y));
    o[2] = (_Float16)(w * ((v.z - mu) * rs * g.z + b.z));
    o[3] = (_Float16)(w * ((v.w - mu) * rs * g.w + b.w));
    *(f16x4*)(y + (size_t)node * F + lane * 4) = o;
}

// ---------------- aligned src-sweep hop v2: run-grouped register accumulation ----------------
// 250 blocks x 1024 thr, 1 block/CU. Block owns 400 dst nodes; wave owns 25.
// Edges sorted by (bucket, node): per-node runs accumulate in fp32 regs (4-deep MLP),
// ONE LDS RMW per (node,bucket). Soft global barrier between src-phases (locality only).
template <int LAST>
__global__ __launch_bounds__(1024) void k_hop2(const _Float16* __restrict__ x, _Float16* __restrict__ y,
                                               const int* __restrict__ ebs, const unsigned char* __restrict__ cnts,
                                               const int* __restrict__ col2, const float* __restrict__ norm,
                                               int P, int* __restrict__ bar) {
    __shared__ _Float16 accu[400 * 128];   // 102,400 B
    int t = threadIdx.x;
    int wave = __builtin_amdgcn_readfirstlane(t >> 6);
    int lane = t & 63;
    int gw = blockIdx.x * 16 + wave;       // 0..3999
    int bb = gw / 40, lw = gw % 40;
    const unsigned char* cbase = cnts + (size_t)bb * 7000 + lw * 175;
    for (int i = t; i < 25600; i += 1024) ((int*)accu)[i] = 0;
    __syncthreads();
    const _Float16* xb = x + P * 128;
    for (int sb = 0; sb < NSB; sb++) {
        int cl = (lane < 25) ? (int)cbase[sb * 25 + lane] : 0;
        int e = ebs[gw * NSB + sb];
        for (int ln = 0; ln < 25; ln++) {
            int cnt = __shfl(cl, ln, 64);
            if (cnt == 0) continue;
            float a0 = 0.f, a1 = 0.f;
            int k = 0;
            for (; k + 4 <= cnt; k += 4) {
                int s0 = col2[e + k], s1 = col2[e + k + 1], s2 = col2[e + k + 2], s3 = col2[e + k + 3];
                f16x2 v0 = *(const f16x2*)(xb + (size_t)s0 * F + lane * 2);
                f16x2 v1 = *(const f16x2*)(xb + (size_t)s1 * F + lane * 2);
                f16x2 v2 = *(const f16x2*)(xb + (size_t)s2 * F + lane * 2);
                f16x2 v3 = *(const f16x2*)(xb + (size_t)s3 * F + lane * 2);
                a0 += ((float)v0[0] + (float)v1[0]) + ((float)v2[0] + (float)v3[0]);
                a1 += ((float)v0[1] + (float)v1[1]) + ((float)v2[1] + (float)v3[1]);
            }
            if (k + 2 <= cnt) {
                int s0 = col2[e + k], s1 = col2[e + k + 1];
                f16x2 v0 = *(const f16x2*)(xb + (size_t)s0 * F + lane * 2);
                f16x2 v1 = *(const f16x2*)(xb + (size_t)s1 * F + lane * 2);
                a0 += (float)v0[0] + (float)v1[0];
                a1 += (float)v0[1] + (float)v1[1];
                k += 2;
            }
            if (k < cnt) {
                int s0 = col2[e + k];
                f16x2 v0 = *(const f16x2*)(xb + (size_t)s0 * F + lane * 2);
                a0 += (float)v0[0];
                a1 += (float)v0[1];
            }
            e += cnt;
            f16x2* p = (f16x2*)&accu[((wave * 25 + ln) << 7) + (lane << 1)];
            f16x2 o = *p;
            o[0] = o[0] + (_Float16)a0;
            o[1] = o[1] + (_Float16)a1;
            *p = o;
        }
        if (sb < NSB - 1) {
            __syncthreads();
            if (t == 0) {
                __hip_atomic_fetch_add(bar, 1, __ATOMIC_RELAXED, __HIP_MEMORY_SCOPE_AGENT);
                int target = HOPBLK * (sb + 1);
                int it = 0;
                while (__hip_atomic_load(bar, __ATOMIC_RELAXED, __HIP_MEMORY_SCOPE_AGENT) < target
                       && ++it < 4096)
                    __builtin_amdgcn_s_sleep(4);
            }
            __syncthreads();
        }
    }
    __syncthreads();
    // write out: 400 nodes x 64 f16x2 slots
    for (int i = t; i < 400 * 64; i += 1024) {
        int nl = i >> 6, lp = i & 63;
        int node = blockIdx.x * 400 + nl;
        float wd = norm[node];
        float sc = LAST ? wd : wd * wd;
        f16x2 a = *(f16x2*)&accu[(nl << 7) + lp * 2];
        f16x2 o;
        o[0] = (_Float16)((float)a[0] * sc);
        o[1] = (_Float16)((float)a[1] * sc);
        *(f16x2*)(y + (size_t)node * F + P * 128 + lp * 2) = o;
    }
}

// ---------------- fp32 -> fp16 cast of both weight matrices ----------------
__global__ __launch_bounds__(256) void k_castW(const float4* __restrict__ Wc, const float4* __restrict__ Wf,
                                               f16x4* __restrict__ WcO, f16x4* __restrict__ WfO) {
    int i = blockIdx.x * 256 + threadIdx.x;
    if (i < F * F / 4) {
        float4 v = Wc[i];
        f16x4 o;
        o[0] = (_Float16)v.x; o[1] = (_Float16)v.y; o[2] = (_Float16)v.z; o[3] = (_Float16)v.w;
        WcO[i] = o;
    } else {
        int j = i - F * F / 4;
        if (j < NCLS * F / 4) {
            float4 v = Wf[j];
            f16x4 o;
            o[0] = (_Float16)v.x; o[1] = (_Float16)v.y; o[2] = (_Float16)v.z; o[3] = (_Float16)v.w;
            WfO[j] = o;
        }
    }
}

// ---------------- fused GEMM: relu(h3 @ Wc^T + bc) @ Wf^T + bf ----------------
__global__ __launch_bounds__(256) void k_gemm(const _Float16* __restrict__ A,
                                              const _Float16* __restrict__ Wc, const float* __restrict__ bc,
                                              const _Float16* __restrict__ Wf, const float* __restrict__ bf,
                                              float* __restrict__ out) {
    __shared__ _Float16 mid[16][264];
    int wave = threadIdx.x >> 6, lane = threadIdx.x & 63;
    int l15 = lane & 15, lhi = lane >> 4;
    int row0 = blockIdx.x * 16;
    const _Float16* arow = A + (size_t)(row0 + l15) * F + lhi * 8;
    int ncol0 = wave * 64;
    f32x4 acc[4];
    for (int t = 0; t < 4; t++) acc[t] = (f32x4){0.f, 0.f, 0.f, 0.f};
#pragma unroll
    for (int kt = 0; kt < 8; kt++) {
        f16x8 a = *(const f16x8*)(arow + kt * 32);
#pragma unroll
        for (int t = 0; t < 4; t++) {
            int n = ncol0 + t * 16 + l15;
            f16x8 b = *(const f16x8*)(Wc + (size_t)n * F + lhi * 8 + kt * 32);
            acc[t] = __builtin_amdgcn_mfma_f32_16x16x32_f16(a, b, acc[t], 0, 0, 0);
        }
    }
#pragma unroll
    for (int t = 0; t < 4; t++) {
        int colb = ncol0 + t * 16 + l15;
        float bv = bc[colb];
#pragma unroll
        for (int r = 0; r < 4; r++) {
            float v = acc[t][r] + bv;
            mid[lhi * 4 + r][colb] = (_Float16)(v > 0.f ? v : 0.f);
        }
    }
    __syncthreads();
    f32x4 acc2 = (f32x4){0.f, 0.f, 0.f, 0.f};
    int colb = wave * 16 + l15;
    const _Float16* brow = Wf + (size_t)colb * F + lhi * 8;
#pragma unroll
    for (int kt = 0; kt < 8; kt++) {
        f16x8 a = *(const f16x8*)&mid[l15][lhi * 8 + kt * 32];
        f16x8 b = *(const f16x8*)(brow + kt * 32);
        acc2 = __builtin_amdgcn_mfma_f32_16x16x32_f16(a, b, acc2, 0, 0, 0);
    }
    float bv = bf[colb];
#pragma unroll
    for (int r = 0; r < 4; r++) {
        int row = row0 + lhi * 4 + r;
        out[(size_t)row * NCLS + colb] = acc2[r] + bv;
    }
}

extern "C" void kernel_launch(void* const* d_in, const int* in_sizes, int n_in,
                              void* d_out, int out_size, void* d_ws, size_t ws_size,
                              hipStream_t stream) {
    const float* features = (const float*)d_in[0];
    const int* edge_src = (const int*)d_in[1];
    const int* edge_dst = (const int*)d_in[2];
    const float* ln_gamma = (const float*)d_in[3];
    const float* ln_beta = (const float*)d_in[4];
    const float* W_conv = (const float*)d_in[5];
    const float* b_conv = (const float*)d_in[6];
    const float* W_fc = (const float*)d_in[7];
    const float* b_fc = (const float*)d_in[8];
    float* out = (float*)d_out;

    char* w = (char*)d_ws;
    const size_t HB2 = (size_t)NND * F * 2;            // 51,200,000 (fp16 h)
    _Float16* hA = (_Float16*)(w + 0);
    int2* binned = (int2*)(w + 0);                     // 28.8 MB, aliases hA (dead before k_ln)
    _Float16* hB = (_Float16*)(w + HB2);
    int* col2 = (int*)(w + 102400000);                 // 14.4 MB
    float* norm = (float*)(w + 117000000);             // 400 KB
    int* ebs = (int*)(w + 117400000);                  // 112 KB
    unsigned char* cnts = (unsigned char*)(w + 117520000); // 700 KB
    int* gcur = (int*)(w + 118300000);                 // 400 B
    int* bar = (int*)(w + 118302048);                  // 6 counters
    _Float16* Wc16 = (_Float16*)(w + 118303072);
    _Float16* Wf16 = (_Float16*)(w + 118434144);

    k_init<<<1, 128, 0, stream>>>(gcur);
    k_passA<<<(NED + EBLK - 1) / EBLK, 256, 0, stream>>>(edge_src, edge_dst, gcur, binned);
    k_passB<<<NC, 1024, 0, stream>>>(binned, gcur, norm, col2, ebs, cnts);

    k_ln<<<NND / 4, 256, 0, stream>>>(features, ln_gamma, ln_beta, norm, hA);

    hipMemsetAsync(bar, 0, 64, stream);
    k_hop2<0><<<HOPBLK, 1024, 0, stream>>>(hA, hB, ebs, cnts, col2, norm, 0, bar + 0);
    k_hop2<0><<<HOPBLK, 1024, 0, stream>>>(hA, hB, ebs, cnts, col2, norm, 1, bar + 1);
    k_hop2<0><<<HOPBLK, 1024, 0, stream>>>(hB, hA, ebs, cnts, col2, norm, 0, bar + 2);
    k_hop2<0><<<HOPBLK, 1024, 0, stream>>>(hB, hA, ebs, cnts, col2, norm, 1, bar + 3);
    k_hop2<1><<<HOPBLK, 1024, 0, stream>>>(hA, hB, ebs, cnts, col2, norm, 0, bar + 4);
    k_hop2<1><<<HOPBLK, 1024, 0, stream>>>(hA, hB, ebs, cnts, col2, norm, 1, bar + 5);

    k_castW<<<(F * F / 4 + NCLS * F / 4 + 255) / 256, 256, 0, stream>>>(
        (const float4*)W_conv, (const float4*)W_fc, (f16x4*)Wc16, (f16x4*)Wf16);

    k_gemm<<<NND / 16, 256, 0, stream>>>(hB, Wc16, b_conv, Wf16, b_fc, out);
}